// Round 5
// baseline (150.725 us; speedup 1.0000x reference)
//
#include <hip/hip_runtime.h>
#include <math.h>

#define B 8
#define S 1024
#define L 2048
#define D 1024

// ---- workspace layout (floats) ----
#define WS_E 0                   // [B*L]    unnormalized exp scores (0 if masked)
#define WS_DL 16384              // [B*S]    dec·(w1+w3) + b_pgen
#define WS_PART 24576            // [B*64*D] partial unnormalized ctx
#define WS_CNT_BYTE ((24576 + 524288) * 4)  // int cnt[16]: [0..7]=enc per-b, [8..15]=dec per-b

__device__ __forceinline__ float dot4(float4 a, float4 b) {
    return a.x * b.x + a.y * b.y + a.z * b.z + a.w * b.w;
}

// Single persistent kernel, 832 blocks (all co-resident at 4 blocks/CU):
//   [0,64)    ENC producers: ch=bid, batches b=0..7 sequentially -> e, part; signal cnt[b]
//   [64,320)  DEC producers: 32 rows each -> dl; signal cnt[8+b]; last block of each
//             batch also runs the C-unit (p_gen) after waiting on both counters
//   [320,832) WRITERS: 3 units each of 1536; unit u: b=u&7, w=u>>3;
//             w<64 -> out2 ctx slice (ds=w&3, ss=w>>2); w>=64 -> out0 pw rows (a=w-64)
__global__ __launch_bounds__(256, 4) void k_mega(
    const float* __restrict__ enc, const float* __restrict__ dec,
    const int* __restrict__ mask, const float* __restrict__ w_ptr,
    const float* __restrict__ b_ptr, const float* __restrict__ w_pgen,
    const float* __restrict__ b_pgen, float* __restrict__ ws,
    int* __restrict__ cnt, float* __restrict__ out) {
    __shared__ float lds[4 * D];  // 16KB
    __shared__ float red[4];
    float4* lds4 = (float4*)lds;
    const int t = threadIdx.x;
    const int w = t >> 6, l = t & 63;
    const int bid = blockIdx.x;

    float4* out0 = (float4*)out;
    float4* out1 = (float4*)(out + (size_t)B * S * L);
    float4* out2 = (float4*)(out + (size_t)B * S * L + B * S);
    const float4* e4 = (const float4*)(ws + WS_E);
    const float4* part4 = (const float4*)(ws + WS_PART);
    const float4* dl4 = (const float4*)(ws + WS_DL);

    if (bid < 64) {
        // ================= ENC producer =================
        const int ch = bid;
        const float4* wp = (const float4*)(w_ptr + D);
        float4 u0 = wp[l], u1 = wp[l + 64], u2 = wp[l + 128], u3 = wp[l + 192];
        float bp = b_ptr[0];
        for (int b = 0; b < B; ++b) {
            float4 a0 = make_float4(0, 0, 0, 0), a1 = a0, a2 = a0, a3 = a0;
#pragma unroll
            for (int jj = 0; jj < 8; ++jj) {
                int row = b * L + ch * 32 + w * 8 + jj;
                float e = 0.f;
                if (mask[row] != 0) {
                    const float4* rp = (const float4*)(enc + (size_t)row * D);
                    float4 v0 = rp[l], v1 = rp[l + 64], v2 = rp[l + 128],
                           v3 = rp[l + 192];
                    float pd = dot4(v0, u0) + dot4(v1, u1) + dot4(v2, u2) +
                               dot4(v3, u3);
#pragma unroll
                    for (int off = 32; off > 0; off >>= 1)
                        pd += __shfl_xor(pd, off, 64);
                    e = expf(pd + bp);
                    a0.x += e * v0.x; a0.y += e * v0.y; a0.z += e * v0.z; a0.w += e * v0.w;
                    a1.x += e * v1.x; a1.y += e * v1.y; a1.z += e * v1.z; a1.w += e * v1.w;
                    a2.x += e * v2.x; a2.y += e * v2.y; a2.z += e * v2.z; a2.w += e * v2.w;
                    a3.x += e * v3.x; a3.y += e * v3.y; a3.z += e * v3.z; a3.w += e * v3.w;
                }
                if (l == 0) ws[WS_E + row] = e;
            }
            float4* lp = lds4 + w * 256;
            lp[l] = a0; lp[l + 64] = a1; lp[l + 128] = a2; lp[l + 192] = a3;
            __syncthreads();
            float4 s0 = lds4[t], s1 = lds4[256 + t], s2 = lds4[512 + t],
                   s3 = lds4[768 + t];
            float4 r;
            r.x = (s0.x + s1.x) + (s2.x + s3.x);
            r.y = (s0.y + s1.y) + (s2.y + s3.y);
            r.z = (s0.z + s1.z) + (s2.z + s3.z);
            r.w = (s0.w + s1.w) + (s2.w + s3.w);
            ((float4*)(ws + WS_PART))[(b * 64 + ch) * 256 + t] = r;
            __syncthreads();  // drains stores (vmcnt) + protects LDS reuse
            if (t == 0) {
                __builtin_amdgcn_fence(__ATOMIC_RELEASE, "agent");
                __hip_atomic_fetch_add(&cnt[b], 1, __ATOMIC_RELAXED,
                                       __HIP_MEMORY_SCOPE_AGENT);
            }
        }
        return;
    }

    if (bid < 320) {
        // ================= DEC producer =================
        int i = bid - 64;  // [0,256), 32 rows each; 32 blocks per batch
        int b = i >> 5;
        const float4* w1 = (const float4*)(w_pgen);
        const float4* w3 = (const float4*)(w_pgen + 2 * D);
        float4 c0, c1, c2, c3;
        {
            float4 x, y;
            x = w1[l];       y = w3[l];       c0 = make_float4(x.x + y.x, x.y + y.y, x.z + y.z, x.w + y.w);
            x = w1[l + 64];  y = w3[l + 64];  c1 = make_float4(x.x + y.x, x.y + y.y, x.z + y.z, x.w + y.w);
            x = w1[l + 128]; y = w3[l + 128]; c2 = make_float4(x.x + y.x, x.y + y.y, x.z + y.z, x.w + y.w);
            x = w1[l + 192]; y = w3[l + 192]; c3 = make_float4(x.x + y.x, x.y + y.y, x.z + y.z, x.w + y.w);
        }
        float bpg = b_pgen[0];
#pragma unroll
        for (int jj = 0; jj < 8; ++jj) {
            int r = i * 32 + w * 8 + jj;  // [0, B*S)
            const float4* row = (const float4*)(dec + (size_t)r * D);
            float acc = dot4(row[l], c0) + dot4(row[l + 64], c1) +
                        dot4(row[l + 128], c2) + dot4(row[l + 192], c3);
#pragma unroll
            for (int off = 32; off > 0; off >>= 1) acc += __shfl_xor(acc, off, 64);
            if (l == 0) ws[WS_DL + r] = acc + bpg;
        }
        __syncthreads();
        if (t == 0) {
            __builtin_amdgcn_fence(__ATOMIC_RELEASE, "agent");
            __hip_atomic_fetch_add(&cnt[8 + b], 1, __ATOMIC_RELAXED,
                                   __HIP_MEMORY_SCOPE_AGENT);
        }
        if ((i & 31) == 31) {
            // ---- C-unit: p_gen for batch b ----
            __syncthreads();
            if (t == 0) {
                while (__hip_atomic_load(&cnt[b], __ATOMIC_RELAXED,
                                         __HIP_MEMORY_SCOPE_AGENT) < 64)
                    __builtin_amdgcn_s_sleep(4);
                while (__hip_atomic_load(&cnt[8 + b], __ATOMIC_RELAXED,
                                         __HIP_MEMORY_SCOPE_AGENT) < 32)
                    __builtin_amdgcn_s_sleep(4);
                __builtin_amdgcn_fence(__ATOMIC_ACQUIRE, "agent");
            }
            __syncthreads();
            float4 v1 = e4[b * 512 + t], v2 = e4[b * 512 + 256 + t];
            float s = (v1.x + v1.y + v1.z + v1.w) + (v2.x + v2.y + v2.z + v2.w);
#pragma unroll
            for (int off = 32; off > 0; off >>= 1) s += __shfl_xor(s, off, 64);
            if (l == 0) red[w] = s;
            __syncthreads();
            float inv = 1.0f / ((red[0] + red[1]) + (red[2] + red[3]));
            float4 c = make_float4(0, 0, 0, 0);
#pragma unroll 8
            for (int ch = 0; ch < 64; ++ch) {
                float4 p = part4[(b * 64 + ch) * 256 + t];
                c.x += p.x; c.y += p.y; c.z += p.z; c.w += p.w;
            }
            float4 w2 = ((const float4*)(w_pgen + D))[t];
            float cacc = dot4(c, w2);
#pragma unroll
            for (int off = 32; off > 0; off >>= 1) cacc += __shfl_xor(cacc, off, 64);
            __syncthreads();
            if (l == 0) red[w] = cacc;
            __syncthreads();
            float cw = inv * ((red[0] + red[1]) + (red[2] + red[3]));
            float4 dl = dl4[b * 256 + t];
            float4 o;
            o.x = 1.0f / (1.0f + expf(-(dl.x + cw)));
            o.y = 1.0f / (1.0f + expf(-(dl.y + cw)));
            o.z = 1.0f / (1.0f + expf(-(dl.z + cw)));
            o.w = 1.0f / (1.0f + expf(-(dl.w + cw)));
            out1[b * 256 + t] = o;
        }
        return;
    }

    // ================= WRITERS =================
    int k = bid - 320;  // [0,512), 3 units each
    for (int m = 0; m < 3; ++m) {
        int u = k * 3 + m;  // [0,1536)
        int b = u & 7;
        int wu = u >> 3;  // [0,192)
        __syncthreads();
        if (t == 0) {
            while (__hip_atomic_load(&cnt[b], __ATOMIC_RELAXED,
                                     __HIP_MEMORY_SCOPE_AGENT) < 64)
                __builtin_amdgcn_s_sleep(4);
            __builtin_amdgcn_fence(__ATOMIC_ACQUIRE, "agent");
        }
        __syncthreads();
        // per-b inv (recomputed per unit from the small e table)
        float4 v1 = e4[b * 512 + t], v2 = e4[b * 512 + 256 + t];
        float s = (v1.x + v1.y + v1.z + v1.w) + (v2.x + v2.y + v2.z + v2.w);
#pragma unroll
        for (int off = 32; off > 0; off >>= 1) s += __shfl_xor(s, off, 64);
        if (l == 0) red[w] = s;
        if (wu >= 64) { lds4[t] = v1; lds4[256 + t] = v2; }
        __syncthreads();
        float inv = 1.0f / ((red[0] + red[1]) + (red[2] + red[3]));
        if (wu < 64) {
            // ---- B-unit: out2 ctx slice (b, ds, ss) ----
            int ds = wu & 3;
            int ss = wu >> 2;
            int d4 = t & 63;
            int chg = t >> 6;
            float4 c = make_float4(0, 0, 0, 0);
#pragma unroll
            for (int kk = 0; kk < 16; ++kk) {
                int ch = chg + kk * 4;
                float4 p = part4[(b * 64 + ch) * 256 + ds * 64 + d4];
                c.x += p.x; c.y += p.y; c.z += p.z; c.w += p.w;
            }
            lds4[chg * 64 + d4] = c;
            __syncthreads();
            if (t < 64) {
                float4 a0 = lds4[t], a1 = lds4[64 + t], a2 = lds4[128 + t],
                       a3 = lds4[192 + t];
                float4 cx;
                cx.x = ((a0.x + a1.x) + (a2.x + a3.x)) * inv;
                cx.y = ((a0.y + a1.y) + (a2.y + a3.y)) * inv;
                cx.z = ((a0.z + a1.z) + (a2.z + a3.z)) * inv;
                cx.w = ((a0.w + a1.w) + (a2.w + a3.w)) * inv;
                lds4[256 + t] = cx;
            }
            __syncthreads();
#pragma unroll
            for (int it = 0; it < 16; ++it) {
                int flat = it * 256 + t;
                int s_loc = flat >> 6;
                int dloc = flat & 63;
                out2[((size_t)(b * S + ss * 64 + s_loc)) * 256 + ds * 64 + dloc] =
                    lds4[256 + dloc];
            }
        } else {
            // ---- A-unit: out0 pw rows (b, a) ----
            int a = wu - 64;  // [0,128)
#pragma unroll
            for (int it = 0; it < 16; ++it) {
                int flat = it * 256 + t;
                int s_loc = flat >> 9;
                int l4 = flat & 511;
                float4 e = lds4[l4];
                float4 o;
                o.x = e.x * inv; o.y = e.y * inv; o.z = e.z * inv; o.w = e.w * inv;
                out0[((size_t)(b * S + a * 8 + s_loc)) * 512 + l4] = o;
            }
        }
    }
}

extern "C" void kernel_launch(void* const* d_in, const int* in_sizes, int n_in,
                              void* d_out, int out_size, void* d_ws, size_t ws_size,
                              hipStream_t stream) {
    (void)in_sizes; (void)n_in; (void)out_size; (void)ws_size;
    const float* dec = (const float*)d_in[0];
    const float* enc = (const float*)d_in[1];
    const int* mask = (const int*)d_in[2];
    const float* w_ptr = (const float*)d_in[4];
    const float* b_ptr = (const float*)d_in[5];
    const float* w_pgen = (const float*)d_in[6];
    const float* b_pgen = (const float*)d_in[7];
    float* out = (float*)d_out;
    float* ws = (float*)d_ws;
    int* cnt = (int*)((char*)d_ws + WS_CNT_BYTE);

    hipMemsetAsync(cnt, 0, 16 * sizeof(int), stream);
    k_mega<<<832, 256, 0, stream>>>(enc, dec, mask, w_ptr, b_ptr, w_pgen,
                                    b_pgen, ws, cnt, out);
}

// Round 6
// 113.475 us; speedup vs baseline: 1.3283x; 1.3283x over previous
//
#include <hip/hip_runtime.h>
#include <math.h>

#define B 8
#define S 1024
#define L 2048
#define D 1024

// ---- workspace layout (floats) ----
#define WS_E 0                   // [B*L]    unnormalized exp scores (0 if masked)
#define WS_DL 16384              // [B*S]    dec·(w1+w3) + b_pgen
#define WS_PART 24576            // [B*64*D] partial unnormalized ctx
#define WS_CNT_BYTE ((24576 + 524288) * 4)  // int cnt[16]: [0..7]=enc per-b, [8..15]=dec per-b

__device__ __forceinline__ float dot4(float4 a, float4 b) {
    return a.x * b.x + a.y * b.y + a.z * b.z + a.w * b.w;
}

// Single persistent kernel, 768 blocks (3/CU co-resident):
//   [0,512)   ENC producers: one (b=bid>>6, ch=bid&63) chunk each -> e, part; signal cnt[b]
//   [512,768) DEC producers: 32 rows each -> dl; signal cnt[8+b]; last block per batch
//             runs the C-unit (p_gen) after waiting on cnt[b] and cnt[8+b]
//   then EVERY block: 2 writer units (1536 total; 192 per batch: 128 A=out0, 64 B=out2),
//   each spinning only on cnt[b] (enc complete for that batch).
__global__ __launch_bounds__(256, 3) void k_mega(
    const float* __restrict__ enc, const float* __restrict__ dec,
    const int* __restrict__ mask, const float* __restrict__ w_ptr,
    const float* __restrict__ b_ptr, const float* __restrict__ w_pgen,
    const float* __restrict__ b_pgen, float* __restrict__ ws,
    int* __restrict__ cnt, float* __restrict__ out) {
    __shared__ float lds[4 * D];  // 16KB
    __shared__ float red[4];
    float4* lds4 = (float4*)lds;
    const int t = threadIdx.x;
    const int w = t >> 6, l = t & 63;
    const int bid = blockIdx.x;

    float4* out0 = (float4*)out;
    float4* out1 = (float4*)(out + (size_t)B * S * L);
    float4* out2 = (float4*)(out + (size_t)B * S * L + B * S);
    const float4* e4 = (const float4*)(ws + WS_E);
    const float4* part4 = (const float4*)(ws + WS_PART);
    const float4* dl4 = (const float4*)(ws + WS_DL);

    if (bid < 512) {
        // ================= ENC producer (one chunk) =================
        const int b = bid >> 6;
        const int ch = bid & 63;
        const float4* wp = (const float4*)(w_ptr + D);
        float4 u0 = wp[l], u1 = wp[l + 64], u2 = wp[l + 128], u3 = wp[l + 192];
        float bp = b_ptr[0];
        float4 a0 = make_float4(0, 0, 0, 0), a1 = a0, a2 = a0, a3 = a0;
#pragma unroll
        for (int jj = 0; jj < 8; ++jj) {
            int row = b * L + ch * 32 + w * 8 + jj;
            float e = 0.f;
            if (mask[row] != 0) {
                const float4* rp = (const float4*)(enc + (size_t)row * D);
                float4 v0 = rp[l], v1 = rp[l + 64], v2 = rp[l + 128],
                       v3 = rp[l + 192];
                float pd = dot4(v0, u0) + dot4(v1, u1) + dot4(v2, u2) +
                           dot4(v3, u3);
#pragma unroll
                for (int off = 32; off > 0; off >>= 1)
                    pd += __shfl_xor(pd, off, 64);
                e = expf(pd + bp);
                a0.x += e * v0.x; a0.y += e * v0.y; a0.z += e * v0.z; a0.w += e * v0.w;
                a1.x += e * v1.x; a1.y += e * v1.y; a1.z += e * v1.z; a1.w += e * v1.w;
                a2.x += e * v2.x; a2.y += e * v2.y; a2.z += e * v2.z; a2.w += e * v2.w;
                a3.x += e * v3.x; a3.y += e * v3.y; a3.z += e * v3.z; a3.w += e * v3.w;
            }
            if (l == 0) ws[WS_E + row] = e;
        }
        float4* lp = lds4 + w * 256;
        lp[l] = a0; lp[l + 64] = a1; lp[l + 128] = a2; lp[l + 192] = a3;
        __syncthreads();
        float4 s0 = lds4[t], s1 = lds4[256 + t], s2 = lds4[512 + t],
               s3 = lds4[768 + t];
        float4 r;
        r.x = (s0.x + s1.x) + (s2.x + s3.x);
        r.y = (s0.y + s1.y) + (s2.y + s3.y);
        r.z = (s0.z + s1.z) + (s2.z + s3.z);
        r.w = (s0.w + s1.w) + (s2.w + s3.w);
        ((float4*)(ws + WS_PART))[(b * 64 + ch) * 256 + t] = r;
        __syncthreads();
        if (t == 0) {
            __builtin_amdgcn_fence(__ATOMIC_RELEASE, "agent");
            __hip_atomic_fetch_add(&cnt[b], 1, __ATOMIC_RELAXED,
                                   __HIP_MEMORY_SCOPE_AGENT);
        }
    } else {
        // ================= DEC producer =================
        int i = bid - 512;  // [0,256), 32 rows each; 32 blocks per batch
        int b = i >> 5;
        const float4* w1 = (const float4*)(w_pgen);
        const float4* w3 = (const float4*)(w_pgen + 2 * D);
        float4 c0, c1, c2, c3;
        {
            float4 x, y;
            x = w1[l];       y = w3[l];       c0 = make_float4(x.x + y.x, x.y + y.y, x.z + y.z, x.w + y.w);
            x = w1[l + 64];  y = w3[l + 64];  c1 = make_float4(x.x + y.x, x.y + y.y, x.z + y.z, x.w + y.w);
            x = w1[l + 128]; y = w3[l + 128]; c2 = make_float4(x.x + y.x, x.y + y.y, x.z + y.z, x.w + y.w);
            x = w1[l + 192]; y = w3[l + 192]; c3 = make_float4(x.x + y.x, x.y + y.y, x.z + y.z, x.w + y.w);
        }
        float bpg = b_pgen[0];
#pragma unroll
        for (int jj = 0; jj < 8; ++jj) {
            int r = i * 32 + w * 8 + jj;  // [0, B*S)
            const float4* row = (const float4*)(dec + (size_t)r * D);
            float acc = dot4(row[l], c0) + dot4(row[l + 64], c1) +
                        dot4(row[l + 128], c2) + dot4(row[l + 192], c3);
#pragma unroll
            for (int off = 32; off > 0; off >>= 1) acc += __shfl_xor(acc, off, 64);
            if (l == 0) ws[WS_DL + r] = acc + bpg;
        }
        __syncthreads();
        if (t == 0) {
            __builtin_amdgcn_fence(__ATOMIC_RELEASE, "agent");
            __hip_atomic_fetch_add(&cnt[8 + b], 1, __ATOMIC_RELAXED,
                                   __HIP_MEMORY_SCOPE_AGENT);
        }
        if ((i & 31) == 31) {
            // ---- C-unit: p_gen for batch b ----
            __syncthreads();
            if (t == 0) {
                while (__hip_atomic_load(&cnt[b], __ATOMIC_RELAXED,
                                         __HIP_MEMORY_SCOPE_AGENT) < 64)
                    __builtin_amdgcn_s_sleep(2);
                while (__hip_atomic_load(&cnt[8 + b], __ATOMIC_RELAXED,
                                         __HIP_MEMORY_SCOPE_AGENT) < 32)
                    __builtin_amdgcn_s_sleep(2);
                __builtin_amdgcn_fence(__ATOMIC_ACQUIRE, "agent");
            }
            __syncthreads();
            float4 v1 = e4[b * 512 + t], v2 = e4[b * 512 + 256 + t];
            float s = (v1.x + v1.y + v1.z + v1.w) + (v2.x + v2.y + v2.z + v2.w);
#pragma unroll
            for (int off = 32; off > 0; off >>= 1) s += __shfl_xor(s, off, 64);
            if (l == 0) red[w] = s;
            __syncthreads();
            float inv = 1.0f / ((red[0] + red[1]) + (red[2] + red[3]));
            float4 c = make_float4(0, 0, 0, 0);
#pragma unroll 8
            for (int ch = 0; ch < 64; ++ch) {
                float4 p = part4[(b * 64 + ch) * 256 + t];
                c.x += p.x; c.y += p.y; c.z += p.z; c.w += p.w;
            }
            float4 w2 = ((const float4*)(w_pgen + D))[t];
            float cacc = dot4(c, w2);
#pragma unroll
            for (int off = 32; off > 0; off >>= 1) cacc += __shfl_xor(cacc, off, 64);
            __syncthreads();
            if (l == 0) red[w] = cacc;
            __syncthreads();
            float cw = inv * ((red[0] + red[1]) + (red[2] + red[3]));
            float4 dl = dl4[b * 256 + t];
            float4 o;
            o.x = 1.0f / (1.0f + expf(-(dl.x + cw)));
            o.y = 1.0f / (1.0f + expf(-(dl.y + cw)));
            o.z = 1.0f / (1.0f + expf(-(dl.z + cw)));
            o.w = 1.0f / (1.0f + expf(-(dl.w + cw)));
            out1[b * 256 + t] = o;
        }
    }

    // ================= WRITERS (every block, 2 units) =================
    for (int m = 0; m < 2; ++m) {
        int u = bid * 2 + m;  // [0,1536)
        int b = u / 192;      // 192 units per batch
        int r = u % 192;      // [0,128): A-unit (out0); [128,192): B-unit (out2)
        __syncthreads();      // prior phase's LDS reads complete
        if (t == 0) {
            while (__hip_atomic_load(&cnt[b], __ATOMIC_RELAXED,
                                     __HIP_MEMORY_SCOPE_AGENT) < 64)
                __builtin_amdgcn_s_sleep(2);
            __builtin_amdgcn_fence(__ATOMIC_ACQUIRE, "agent");
        }
        __syncthreads();
        // per-b inv (recomputed per unit from the small L2-resident e table)
        float4 v1 = e4[b * 512 + t], v2 = e4[b * 512 + 256 + t];
        float s = (v1.x + v1.y + v1.z + v1.w) + (v2.x + v2.y + v2.z + v2.w);
#pragma unroll
        for (int off = 32; off > 0; off >>= 1) s += __shfl_xor(s, off, 64);
        if (l == 0) red[w] = s;
        if (r < 128) { lds4[t] = v1; lds4[256 + t] = v2; }
        __syncthreads();
        float inv = 1.0f / ((red[0] + red[1]) + (red[2] + red[3]));
        if (r < 128) {
            // ---- A-unit: out0 pw rows (b, a) ----
            int a = r;
#pragma unroll
            for (int it = 0; it < 16; ++it) {
                int flat = it * 256 + t;
                int s_loc = flat >> 9;
                int l4 = flat & 511;
                float4 e = lds4[l4];
                float4 o;
                o.x = e.x * inv; o.y = e.y * inv; o.z = e.z * inv; o.w = e.w * inv;
                out0[((size_t)(b * S + a * 8 + s_loc)) * 512 + l4] = o;
            }
        } else {
            // ---- B-unit: out2 ctx slice (b, ds, ss) ----
            int wu = r - 128;  // [0,64)
            int ds = wu & 3;
            int ss = wu >> 2;
            int d4 = t & 63;
            int chg = t >> 6;
            float4 c = make_float4(0, 0, 0, 0);
#pragma unroll
            for (int kk = 0; kk < 16; ++kk) {
                int ch = chg + kk * 4;
                float4 p = part4[(b * 64 + ch) * 256 + ds * 64 + d4];
                c.x += p.x; c.y += p.y; c.z += p.z; c.w += p.w;
            }
            lds4[chg * 64 + d4] = c;
            __syncthreads();
            if (t < 64) {
                float4 a0 = lds4[t], a1 = lds4[64 + t], a2 = lds4[128 + t],
                       a3 = lds4[192 + t];
                float4 cx;
                cx.x = ((a0.x + a1.x) + (a2.x + a3.x)) * inv;
                cx.y = ((a0.y + a1.y) + (a2.y + a3.y)) * inv;
                cx.z = ((a0.z + a1.z) + (a2.z + a3.z)) * inv;
                cx.w = ((a0.w + a1.w) + (a2.w + a3.w)) * inv;
                lds4[256 + t] = cx;
            }
            __syncthreads();
#pragma unroll
            for (int it = 0; it < 16; ++it) {
                int flat = it * 256 + t;
                int s_loc = flat >> 6;
                int dloc = flat & 63;
                out2[((size_t)(b * S + ss * 64 + s_loc)) * 256 + ds * 64 + dloc] =
                    lds4[256 + dloc];
            }
        }
    }
}

extern "C" void kernel_launch(void* const* d_in, const int* in_sizes, int n_in,
                              void* d_out, int out_size, void* d_ws, size_t ws_size,
                              hipStream_t stream) {
    (void)in_sizes; (void)n_in; (void)out_size; (void)ws_size;
    const float* dec = (const float*)d_in[0];
    const float* enc = (const float*)d_in[1];
    const int* mask = (const int*)d_in[2];
    const float* w_ptr = (const float*)d_in[4];
    const float* b_ptr = (const float*)d_in[5];
    const float* w_pgen = (const float*)d_in[6];
    const float* b_pgen = (const float*)d_in[7];
    float* out = (float*)d_out;
    float* ws = (float*)d_ws;
    int* cnt = (int*)((char*)d_ws + WS_CNT_BYTE);

    hipMemsetAsync(cnt, 0, 16 * sizeof(int), stream);
    k_mega<<<768, 256, 0, stream>>>(enc, dec, mask, w_ptr, b_ptr, w_pgen,
                                    b_pgen, ws, cnt, out);
}

// Round 7
// 42.628 us; speedup vs baseline: 3.5358x; 2.6620x over previous
//
#include <hip/hip_runtime.h>
#include <math.h>

#define B 8
#define S 1024
#define L 2048
#define D 1024

// ---- workspace layout (floats) ----
#define WS_E 0       // [B*L]    unnormalized exp scores (0 if masked)
#define WS_PART 16384  // [B*64*D] partial unnormalized ctx

__device__ __forceinline__ float dot4(float4 a, float4 b) {
    return a.x * b.x + a.y * b.y + a.z * b.z + a.w * b.w;
}

// K1: enc-only. One (b,ch) chunk of 32 rows per block:
//     e[row] = mask ? exp(enc·w + b_ptr) : 0; part[b,ch,:] = sum e[row]*enc[row,:]
__global__ __launch_bounds__(256) void k_enc(const float* __restrict__ enc,
                                             const int* __restrict__ mask,
                                             const float* __restrict__ w_ptr,
                                             const float* __restrict__ b_ptr,
                                             float* __restrict__ ws) {
    __shared__ float lds[4 * D];
    float4* lds4 = (float4*)lds;
    const int t = threadIdx.x;
    const int w = t >> 6, l = t & 63;
    const int b = blockIdx.x >> 6;
    const int ch = blockIdx.x & 63;
    const float4* wp = (const float4*)(w_ptr + D);
    float4 u0 = wp[l], u1 = wp[l + 64], u2 = wp[l + 128], u3 = wp[l + 192];
    float bp = b_ptr[0];
    float4 a0 = make_float4(0, 0, 0, 0), a1 = a0, a2 = a0, a3 = a0;
#pragma unroll
    for (int jj = 0; jj < 8; ++jj) {
        int row = b * L + ch * 32 + w * 8 + jj;
        float e = 0.f;
        if (mask[row] != 0) {
            const float4* rp = (const float4*)(enc + (size_t)row * D);
            float4 v0 = rp[l], v1 = rp[l + 64], v2 = rp[l + 128], v3 = rp[l + 192];
            float pd = dot4(v0, u0) + dot4(v1, u1) + dot4(v2, u2) + dot4(v3, u3);
#pragma unroll
            for (int off = 32; off > 0; off >>= 1) pd += __shfl_xor(pd, off, 64);
            e = expf(pd + bp);
            a0.x += e * v0.x; a0.y += e * v0.y; a0.z += e * v0.z; a0.w += e * v0.w;
            a1.x += e * v1.x; a1.y += e * v1.y; a1.z += e * v1.z; a1.w += e * v1.w;
            a2.x += e * v2.x; a2.y += e * v2.y; a2.z += e * v2.z; a2.w += e * v2.w;
            a3.x += e * v3.x; a3.y += e * v3.y; a3.z += e * v3.z; a3.w += e * v3.w;
        }
        if (l == 0) ws[WS_E + row] = e;
    }
    float4* lp = lds4 + w * 256;
    lp[l] = a0; lp[l + 64] = a1; lp[l + 128] = a2; lp[l + 192] = a3;
    __syncthreads();
    float4 s0 = lds4[t], s1 = lds4[256 + t], s2 = lds4[512 + t], s3 = lds4[768 + t];
    float4 r;
    r.x = (s0.x + s1.x) + (s2.x + s3.x);
    r.y = (s0.y + s1.y) + (s2.y + s3.y);
    r.z = (s0.z + s1.z) + (s2.z + s3.z);
    r.w = (s0.w + s1.w) + (s2.w + s3.w);
    ((float4*)(ws + WS_PART))[(b * 64 + ch) * 256 + t] = r;
}

// K2: all outputs. Block ranges (dispatch order = overlap order):
//   [0,256)     P — out1: dec reads (HBM, overlap the write stream) + own cw[b]
//   [256,768)   B — out2 ctx slice (b, ds, ss) from L2-resident part
//   [768,1792)  A — out0 pw rows (b, a) from L2-resident e
__global__ __launch_bounds__(256) void k_out(const float* __restrict__ ws,
                                             const float* __restrict__ dec,
                                             const float* __restrict__ w_pgen,
                                             const float* __restrict__ b_pgen,
                                             float* __restrict__ out) {
    __shared__ float4 lds4[512];
    __shared__ float red[4];
    const int t = threadIdx.x;
    const int w = t >> 6, l = t & 63;
    const int bid = blockIdx.x;
    const float4* e4 = (const float4*)(ws + WS_E);
    const float4* part4 = (const float4*)(ws + WS_PART);
    float4* out0 = (float4*)out;
    float* out1 = out + (size_t)B * S * L;
    float4* out2 = (float4*)(out + (size_t)B * S * L + B * S);

    if (bid < 256) {
        // ---- P-unit: p_gen for (b, 32 s-rows) ----
        int b = bid >> 5;
        int sc = bid & 31;
        float4 v1 = e4[b * 512 + t], v2 = e4[b * 512 + 256 + t];
        float s = (v1.x + v1.y + v1.z + v1.w) + (v2.x + v2.y + v2.z + v2.w);
#pragma unroll
        for (int off = 32; off > 0; off >>= 1) s += __shfl_xor(s, off, 64);
        if (l == 0) red[w] = s;
        __syncthreads();
        float inv = 1.0f / ((red[0] + red[1]) + (red[2] + red[3]));
        float4 c = make_float4(0, 0, 0, 0);
#pragma unroll 8
        for (int ch = 0; ch < 64; ++ch) {
            float4 p = part4[(b * 64 + ch) * 256 + t];
            c.x += p.x; c.y += p.y; c.z += p.z; c.w += p.w;
        }
        float4 w2v = ((const float4*)(w_pgen + D))[t];
        float cacc = dot4(c, w2v);
#pragma unroll
        for (int off = 32; off > 0; off >>= 1) cacc += __shfl_xor(cacc, off, 64);
        __syncthreads();
        if (l == 0) red[w] = cacc;
        __syncthreads();
        float cw = inv * ((red[0] + red[1]) + (red[2] + red[3]));
        const float4* w1 = (const float4*)(w_pgen);
        const float4* w3 = (const float4*)(w_pgen + 2 * D);
        float4 c0, c1, c2, c3;
        {
            float4 x, y;
            x = w1[l];       y = w3[l];       c0 = make_float4(x.x + y.x, x.y + y.y, x.z + y.z, x.w + y.w);
            x = w1[l + 64];  y = w3[l + 64];  c1 = make_float4(x.x + y.x, x.y + y.y, x.z + y.z, x.w + y.w);
            x = w1[l + 128]; y = w3[l + 128]; c2 = make_float4(x.x + y.x, x.y + y.y, x.z + y.z, x.w + y.w);
            x = w1[l + 192]; y = w3[l + 192]; c3 = make_float4(x.x + y.x, x.y + y.y, x.z + y.z, x.w + y.w);
        }
        float bpg = b_pgen[0];
#pragma unroll
        for (int jj = 0; jj < 8; ++jj) {
            int r = b * S + sc * 32 + w * 8 + jj;
            const float4* row = (const float4*)(dec + (size_t)r * D);
            float acc = dot4(row[l], c0) + dot4(row[l + 64], c1) +
                        dot4(row[l + 128], c2) + dot4(row[l + 192], c3);
#pragma unroll
            for (int off = 32; off > 0; off >>= 1) acc += __shfl_xor(acc, off, 64);
            if (l == 0) out1[r] = 1.0f / (1.0f + expf(-((acc + bpg) + cw)));
        }
    } else if (bid < 768) {
        // ---- B-unit: out2 ctx slice (b, ds, ss) ----
        int wu = bid - 256;
        int b = wu >> 6;
        int r6 = wu & 63;
        int ds = r6 & 3;
        int ss = r6 >> 2;
        float4 v1 = e4[b * 512 + t], v2 = e4[b * 512 + 256 + t];
        float s = (v1.x + v1.y + v1.z + v1.w) + (v2.x + v2.y + v2.z + v2.w);
#pragma unroll
        for (int off = 32; off > 0; off >>= 1) s += __shfl_xor(s, off, 64);
        if (l == 0) red[w] = s;
        __syncthreads();
        float inv = 1.0f / ((red[0] + red[1]) + (red[2] + red[3]));
        int d4 = t & 63;
        int chg = t >> 6;
        float4 c = make_float4(0, 0, 0, 0);
#pragma unroll
        for (int kk = 0; kk < 16; ++kk) {
            int ch = chg + kk * 4;
            float4 p = part4[(b * 64 + ch) * 256 + ds * 64 + d4];
            c.x += p.x; c.y += p.y; c.z += p.z; c.w += p.w;
        }
        lds4[chg * 64 + d4] = c;
        __syncthreads();
        if (t < 64) {
            float4 a0 = lds4[t], a1 = lds4[64 + t], a2 = lds4[128 + t],
                   a3 = lds4[192 + t];
            float4 cx;
            cx.x = ((a0.x + a1.x) + (a2.x + a3.x)) * inv;
            cx.y = ((a0.y + a1.y) + (a2.y + a3.y)) * inv;
            cx.z = ((a0.z + a1.z) + (a2.z + a3.z)) * inv;
            cx.w = ((a0.w + a1.w) + (a2.w + a3.w)) * inv;
            lds4[256 + t] = cx;
        }
        __syncthreads();
#pragma unroll
        for (int it = 0; it < 16; ++it) {
            int flat = it * 256 + t;
            int s_loc = flat >> 6;
            int dloc = flat & 63;
            out2[((size_t)(b * S + ss * 64 + s_loc)) * 256 + ds * 64 + dloc] =
                lds4[256 + dloc];
        }
    } else {
        // ---- A-unit: out0 pw rows (b, a) ----
        int ab = bid - 768;
        int b = ab >> 7;
        int a = ab & 127;
        float4 v1 = e4[b * 512 + t], v2 = e4[b * 512 + 256 + t];
        lds4[t] = v1;
        lds4[256 + t] = v2;
        float s = (v1.x + v1.y + v1.z + v1.w) + (v2.x + v2.y + v2.z + v2.w);
#pragma unroll
        for (int off = 32; off > 0; off >>= 1) s += __shfl_xor(s, off, 64);
        if (l == 0) red[w] = s;
        __syncthreads();
        float inv = 1.0f / ((red[0] + red[1]) + (red[2] + red[3]));
#pragma unroll
        for (int it = 0; it < 16; ++it) {
            int flat = it * 256 + t;
            int s_loc = flat >> 9;
            int l4 = flat & 511;
            float4 e = lds4[l4];
            float4 o;
            o.x = e.x * inv; o.y = e.y * inv; o.z = e.z * inv; o.w = e.w * inv;
            out0[((size_t)(b * S + a * 8 + s_loc)) * 512 + l4] = o;
        }
    }
}

extern "C" void kernel_launch(void* const* d_in, const int* in_sizes, int n_in,
                              void* d_out, int out_size, void* d_ws, size_t ws_size,
                              hipStream_t stream) {
    (void)in_sizes; (void)n_in; (void)out_size; (void)ws_size;
    const float* dec = (const float*)d_in[0];
    const float* enc = (const float*)d_in[1];
    const int* mask = (const int*)d_in[2];
    const float* w_ptr = (const float*)d_in[4];
    const float* b_ptr = (const float*)d_in[5];
    const float* w_pgen = (const float*)d_in[6];
    const float* b_pgen = (const float*)d_in[7];
    float* out = (float*)d_out;
    float* ws = (float*)d_ws;

    k_enc<<<512, 256, 0, stream>>>(enc, mask, w_ptr, b_ptr, ws);
    k_out<<<1792, 256, 0, stream>>>(ws, dec, w_pgen, b_pgen, out);
}

// Round 8
// 37.457 us; speedup vs baseline: 4.0239x; 1.1380x over previous
//
#include <hip/hip_runtime.h>
#include <math.h>

#define B 8
#define S 1024
#define L 2048
#define D 1024

// ---- workspace layout (floats) ----
#define WS_E 0        // [B*L]    unnormalized exp scores (0 if masked)
#define WS_DL 16384   // [B*S]    dec·(w1+w3) + b_pgen
#define WS_CS 24576   // [B*64]   per-chunk e-sums (fixed-order partials)
#define WS_PART 25088 // [B*64*D] partial unnormalized ctx

typedef float f4v __attribute__((ext_vector_type(4)));
__device__ __forceinline__ void nt_store4(float4* p, float4 v) {
    __builtin_nontemporal_store(*(f4v*)&v, (f4v*)p);
}

__device__ __forceinline__ float dot4(float4 a, float4 b) {
    return a.x * b.x + a.y * b.y + a.z * b.z + a.w * b.w;
}

// deterministic per-b inv: fixed-order 64-chunk-sum reduce, redundant per wave
__device__ __forceinline__ float inv_from_cs(const float* cs, int b, int l) {
    float v = cs[b * 64 + l];
#pragma unroll
    for (int off = 32; off > 0; off >>= 1) v += __shfl_xor(v, off, 64);
    return 1.0f / v;
}

// K1: blocks [0,512): enc chunk (b,ch) of 32 rows — single pass:
//     e, chunk_esum, part[b,ch,:]. blocks [512,2560): dec logits dl.
__global__ __launch_bounds__(256) void k_fused1(const float* __restrict__ enc,
                                                const float* __restrict__ dec,
                                                const int* __restrict__ mask,
                                                const float* __restrict__ w_ptr,
                                                const float* __restrict__ b_ptr,
                                                const float* __restrict__ w_pgen,
                                                const float* __restrict__ b_pgen,
                                                float* __restrict__ ws) {
    __shared__ float lds[4 * D];
    __shared__ float redc[4];
    float4* lds4 = (float4*)lds;
    int w = threadIdx.x >> 6;
    int l = threadIdx.x & 63;
    if (blockIdx.x < 512) {
        int b = blockIdx.x >> 6;
        int ch = blockIdx.x & 63;
        const float4* wp = (const float4*)(w_ptr + D);
        float4 u0 = wp[l], u1 = wp[l + 64], u2 = wp[l + 128], u3 = wp[l + 192];
        float bp = b_ptr[0];
        float4 a0 = make_float4(0, 0, 0, 0), a1 = a0, a2 = a0, a3 = a0;
        float esum_w = 0.f;
#pragma unroll
        for (int jj = 0; jj < 8; ++jj) {
            int row = b * L + ch * 32 + w * 8 + jj;
            float e = 0.f;
            if (mask[row] != 0) {
                const float4* rp = (const float4*)(enc + (size_t)row * D);
                float4 v0 = rp[l], v1 = rp[l + 64], v2 = rp[l + 128],
                       v3 = rp[l + 192];
                float pd = dot4(v0, u0) + dot4(v1, u1) + dot4(v2, u2) +
                           dot4(v3, u3);
#pragma unroll
                for (int off = 32; off > 0; off >>= 1)
                    pd += __shfl_xor(pd, off, 64);
                e = expf(pd + bp);
                a0.x += e * v0.x; a0.y += e * v0.y; a0.z += e * v0.z; a0.w += e * v0.w;
                a1.x += e * v1.x; a1.y += e * v1.y; a1.z += e * v1.z; a1.w += e * v1.w;
                a2.x += e * v2.x; a2.y += e * v2.y; a2.z += e * v2.z; a2.w += e * v2.w;
                a3.x += e * v3.x; a3.y += e * v3.y; a3.z += e * v3.z; a3.w += e * v3.w;
            }
            esum_w += e;
            if (l == 0) ws[WS_E + row] = e;
        }
        float4* lp = lds4 + w * 256;
        lp[l] = a0; lp[l + 64] = a1; lp[l + 128] = a2; lp[l + 192] = a3;
        if (l == 0) redc[w] = esum_w;
        __syncthreads();
        int t = threadIdx.x;
        float4 s0 = lds4[t], s1 = lds4[256 + t], s2 = lds4[512 + t],
               s3 = lds4[768 + t];
        float4 r;
        r.x = (s0.x + s1.x) + (s2.x + s3.x);
        r.y = (s0.y + s1.y) + (s2.y + s3.y);
        r.z = (s0.z + s1.z) + (s2.z + s3.z);
        r.w = (s0.w + s1.w) + (s2.w + s3.w);
        ((float4*)(ws + WS_PART))[(b * 64 + ch) * 256 + t] = r;
        if (t == 0)
            ws[WS_CS + b * 64 + ch] = (redc[0] + redc[1]) + (redc[2] + redc[3]);
    } else {
        int i = blockIdx.x - 512;
        int r = i * 4 + w;  // [0, B*S)
        const float4* row = (const float4*)(dec + (size_t)r * D);
        const float4* w1 = (const float4*)(w_pgen);
        const float4* w3 = (const float4*)(w_pgen + 2 * D);
        float acc = 0.f;
#pragma unroll
        for (int it = 0; it < 4; ++it) {
            int k = l + it * 64;
            float4 a = row[k];
            float4 u = w1[k];
            float4 t3 = w3[k];
            acc += a.x * (u.x + t3.x) + a.y * (u.y + t3.y) +
                   a.z * (u.z + t3.z) + a.w * (u.w + t3.w);
        }
#pragma unroll
        for (int off = 32; off > 0; off >>= 1) acc += __shfl_down(acc, off, 64);
        if (l == 0) ws[WS_DL + r] = acc + b_pgen[0];
    }
}

// K2: 648 blocks, all grid-resident. nt stores for all outputs.
//   [0,8):    C — cw[b] + p_gen (out1)
//   [8,136):  B — out2: (b, ds quarter, ss2 of 256 s-rows); part read 1:16 reuse
//   [136,648) A — out0: (b, a of 16 s-rows); e-row read 1:16 reuse
__global__ __launch_bounds__(256) void k_out(const float* __restrict__ ws,
                                             const float* __restrict__ w_pgen,
                                             float* __restrict__ out) {
    __shared__ float4 lds4[512];
    __shared__ float red[4];
    const int t = threadIdx.x;
    const int w = t >> 6, l = t & 63;
    const int bid = blockIdx.x;
    const float4* e4 = (const float4*)(ws + WS_E);
    const float4* part4 = (const float4*)(ws + WS_PART);
    const float4* dl4 = (const float4*)(ws + WS_DL);
    const float* cs = ws + WS_CS;
    float4* out0 = (float4*)out;
    float4* out1 = (float4*)(out + (size_t)B * S * L);
    float4* out2 = (float4*)(out + (size_t)B * S * L + B * S);

    if (bid < 8) {
        // ---- C: p_gen for batch b ----
        int b = bid;
        float inv = inv_from_cs(cs, b, l);
        float4 c = make_float4(0, 0, 0, 0);
#pragma unroll 8
        for (int ch = 0; ch < 64; ++ch) {
            float4 p = part4[(b * 64 + ch) * 256 + t];
            c.x += p.x; c.y += p.y; c.z += p.z; c.w += p.w;
        }
        float4 w2v = ((const float4*)(w_pgen + D))[t];
        float cacc = dot4(c, w2v);
#pragma unroll
        for (int off = 32; off > 0; off >>= 1) cacc += __shfl_xor(cacc, off, 64);
        if (l == 0) red[w] = cacc;
        __syncthreads();
        float cw = inv * ((red[0] + red[1]) + (red[2] + red[3]));
        float4 dl = dl4[b * 256 + t];
        float4 o;
        o.x = 1.0f / (1.0f + expf(-(dl.x + cw)));
        o.y = 1.0f / (1.0f + expf(-(dl.y + cw)));
        o.z = 1.0f / (1.0f + expf(-(dl.z + cw)));
        o.w = 1.0f / (1.0f + expf(-(dl.w + cw)));
        nt_store4(&out1[b * 256 + t], o);
    } else if (bid < 136) {
        // ---- B: out2 ctx quarter (b, ds) for 256 s-rows (ss2) ----
        int u = bid - 8;
        int b = u >> 4;
        int q = u & 15;
        int ds = q & 3;
        int ss2 = q >> 2;
        float inv = inv_from_cs(cs, b, l);
        int d4 = t & 63;
        int chg = t >> 6;
        float4 c = make_float4(0, 0, 0, 0);
#pragma unroll
        for (int kk = 0; kk < 16; ++kk) {
            int ch = chg + kk * 4;
            float4 p = part4[(b * 64 + ch) * 256 + ds * 64 + d4];
            c.x += p.x; c.y += p.y; c.z += p.z; c.w += p.w;
        }
        lds4[chg * 64 + d4] = c;
        __syncthreads();
        if (t < 64) {
            float4 a0 = lds4[t], a1 = lds4[64 + t], a2 = lds4[128 + t],
                   a3 = lds4[192 + t];
            float4 cx;
            cx.x = ((a0.x + a1.x) + (a2.x + a3.x)) * inv;
            cx.y = ((a0.y + a1.y) + (a2.y + a3.y)) * inv;
            cx.z = ((a0.z + a1.z) + (a2.z + a3.z)) * inv;
            cx.w = ((a0.w + a1.w) + (a2.w + a3.w)) * inv;
            lds4[256 + t] = cx;
        }
        __syncthreads();
#pragma unroll 8
        for (int it = 0; it < 64; ++it) {
            int flat = it * 256 + t;
            int s_loc = flat >> 6;
            int dloc = flat & 63;
            nt_store4(&out2[((size_t)(b * S + ss2 * 256 + s_loc)) * 256 +
                            ds * 64 + dloc],
                      lds4[256 + dloc]);
        }
    } else {
        // ---- A: out0 pw rows (b, a of 16 s-rows) ----
        int u = bid - 136;  // [0,512)
        int b = u >> 6;
        int a = u & 63;
        float inv = inv_from_cs(cs, b, l);
        float4 v1 = e4[b * 512 + t], v2 = e4[b * 512 + 256 + t];
        float4 p1, p2;
        p1.x = v1.x * inv; p1.y = v1.y * inv; p1.z = v1.z * inv; p1.w = v1.w * inv;
        p2.x = v2.x * inv; p2.y = v2.y * inv; p2.z = v2.z * inv; p2.w = v2.w * inv;
        lds4[t] = p1;
        lds4[256 + t] = p2;
        __syncthreads();
#pragma unroll 8
        for (int it = 0; it < 32; ++it) {
            int flat = it * 256 + t;
            int s_loc = flat >> 9;
            int l4 = flat & 511;
            nt_store4(&out0[((size_t)(b * S + a * 16 + s_loc)) * 512 + l4],
                      lds4[l4]);
        }
    }
}

extern "C" void kernel_launch(void* const* d_in, const int* in_sizes, int n_in,
                              void* d_out, int out_size, void* d_ws, size_t ws_size,
                              hipStream_t stream) {
    (void)in_sizes; (void)n_in; (void)out_size; (void)ws_size;
    const float* dec = (const float*)d_in[0];
    const float* enc = (const float*)d_in[1];
    const int* mask = (const int*)d_in[2];
    const float* w_ptr = (const float*)d_in[4];
    const float* b_ptr = (const float*)d_in[5];
    const float* w_pgen = (const float*)d_in[6];
    const float* b_pgen = (const float*)d_in[7];
    float* out = (float*)d_out;
    float* ws = (float*)d_ws;

    k_fused1<<<2560, 256, 0, stream>>>(enc, dec, mask, w_ptr, b_ptr, w_pgen,
                                       b_pgen, ws);
    k_out<<<648, 256, 0, stream>>>(ws, w_pgen, out);
}

// Round 9
// 36.974 us; speedup vs baseline: 4.0765x; 1.0131x over previous
//
#include <hip/hip_runtime.h>
#include <math.h>

#define B 8
#define S 1024
#define L 2048
#define D 1024

// ---- workspace layout (floats) ----
#define WS_E 0        // [B*L]    unnormalized exp scores (0 if masked)
#define WS_CS 16384   // [B*64]   per-chunk e-sums (fixed-order partials)
#define WS_PCW 16896  // [B*64]   per-chunk part·w2 dots
#define WS_PART 17408 // [B*64*D] partial unnormalized ctx

typedef float f4v __attribute__((ext_vector_type(4)));
__device__ __forceinline__ void nt_store4(float4* p, float4 v) {
    __builtin_nontemporal_store(*(f4v*)&v, (f4v*)p);
}

__device__ __forceinline__ float dot4(float4 a, float4 b) {
    return a.x * b.x + a.y * b.y + a.z * b.z + a.w * b.w;
}

__device__ __forceinline__ float wave_sum(float v) {
#pragma unroll
    for (int off = 32; off > 0; off >>= 1) v += __shfl_xor(v, off, 64);
    return v;
}

// K1: enc-only. One (b,ch) chunk of 32 rows per block:
//   e[row], chunk e-sum, part[b,ch,:], and pcw[b,ch] = part_chunk · w_pgen[D:2D].
__global__ __launch_bounds__(256) void k_enc(const float* __restrict__ enc,
                                             const int* __restrict__ mask,
                                             const float* __restrict__ w_ptr,
                                             const float* __restrict__ b_ptr,
                                             const float* __restrict__ w_pgen,
                                             float* __restrict__ ws) {
    __shared__ float lds[4 * D];
    __shared__ float redc[4], redp[4];
    float4* lds4 = (float4*)lds;
    const int t = threadIdx.x;
    const int w = t >> 6, l = t & 63;
    const int b = blockIdx.x >> 6;
    const int ch = blockIdx.x & 63;
    const float4* wp = (const float4*)(w_ptr + D);
    float4 u0 = wp[l], u1 = wp[l + 64], u2 = wp[l + 128], u3 = wp[l + 192];
    float bp = b_ptr[0];
    float4 a0 = make_float4(0, 0, 0, 0), a1 = a0, a2 = a0, a3 = a0;
    float esum_w = 0.f;
#pragma unroll
    for (int jj = 0; jj < 8; ++jj) {
        int row = b * L + ch * 32 + w * 8 + jj;
        float e = 0.f;
        if (mask[row] != 0) {
            const float4* rp = (const float4*)(enc + (size_t)row * D);
            float4 v0 = rp[l], v1 = rp[l + 64], v2 = rp[l + 128], v3 = rp[l + 192];
            float pd = dot4(v0, u0) + dot4(v1, u1) + dot4(v2, u2) + dot4(v3, u3);
#pragma unroll
            for (int off = 32; off > 0; off >>= 1) pd += __shfl_xor(pd, off, 64);
            e = expf(pd + bp);
            a0.x += e * v0.x; a0.y += e * v0.y; a0.z += e * v0.z; a0.w += e * v0.w;
            a1.x += e * v1.x; a1.y += e * v1.y; a1.z += e * v1.z; a1.w += e * v1.w;
            a2.x += e * v2.x; a2.y += e * v2.y; a2.z += e * v2.z; a2.w += e * v2.w;
            a3.x += e * v3.x; a3.y += e * v3.y; a3.z += e * v3.z; a3.w += e * v3.w;
        }
        esum_w += e;
        if (l == 0) ws[WS_E + row] = e;
    }
    float4* lp = lds4 + w * 256;
    lp[l] = a0; lp[l + 64] = a1; lp[l + 128] = a2; lp[l + 192] = a3;
    if (l == 0) redc[w] = esum_w;
    __syncthreads();
    float4 s0 = lds4[t], s1 = lds4[256 + t], s2 = lds4[512 + t], s3 = lds4[768 + t];
    float4 r;
    r.x = (s0.x + s1.x) + (s2.x + s3.x);
    r.y = (s0.y + s1.y) + (s2.y + s3.y);
    r.z = (s0.z + s1.z) + (s2.z + s3.z);
    r.w = (s0.w + s1.w) + (s2.w + s3.w);
    ((float4*)(ws + WS_PART))[(b * 64 + ch) * 256 + t] = r;
    // pcw: this chunk's contribution to ctx·w2 (fixed-order)
    float4 w2v = ((const float4*)(w_pgen + D))[t];
    float pc = wave_sum(dot4(r, w2v));
    if (l == 0) redp[w] = pc;
    __syncthreads();
    if (t == 0) {
        ws[WS_CS + b * 64 + ch] = (redc[0] + redc[1]) + (redc[2] + redc[3]);
        ws[WS_PCW + b * 64 + ch] = (redp[0] + redp[1]) + (redp[2] + redp[3]);
    }
}

// K2: 3328 blocks, roles interleaved by bid%13 so dec reads co-flow with writes:
//   r in [0,8):  D — 4 dec rows -> out1 (cw recomputed from cs/pcw scalars)
//   r in [8,12): A — out0: 8 pw rows (64 KB nt-stores)
//   r == 12:     B — out2: quarter-tile, 128 s-rows (128 KB nt-stores)
__global__ __launch_bounds__(256) void k_out(const float* __restrict__ ws,
                                             const float* __restrict__ dec,
                                             const float* __restrict__ w_pgen,
                                             const float* __restrict__ b_pgen,
                                             float* __restrict__ out) {
    __shared__ float4 lds4[512];
    const int t = threadIdx.x;
    const int w = t >> 6, l = t & 63;
    const int g = blockIdx.x / 13;
    const int r = blockIdx.x % 13;
    const float4* e4 = (const float4*)(ws + WS_E);
    const float4* part4 = (const float4*)(ws + WS_PART);
    const float* cs = ws + WS_CS;
    const float* pcw = ws + WS_PCW;
    float4* out0 = (float4*)out;
    float* out1 = out + (size_t)B * S * L;
    float4* out2 = (float4*)(out + (size_t)B * S * L + B * S);

    if (r < 8) {
        // ---- D-unit: 4 dec rows -> out1 ----
        int du = g * 8 + r;  // [0,2048)
        int b = du >> 8;
        float inv = 1.0f / wave_sum(cs[b * 64 + l]);
        float cw = inv * wave_sum(pcw[b * 64 + l]);
        const float4* w1 = (const float4*)(w_pgen);
        const float4* w3 = (const float4*)(w_pgen + 2 * D);
        float4 c0, c1, c2, c3;
        {
            float4 x, y;
            x = w1[l];       y = w3[l];       c0 = make_float4(x.x + y.x, x.y + y.y, x.z + y.z, x.w + y.w);
            x = w1[l + 64];  y = w3[l + 64];  c1 = make_float4(x.x + y.x, x.y + y.y, x.z + y.z, x.w + y.w);
            x = w1[l + 128]; y = w3[l + 128]; c2 = make_float4(x.x + y.x, x.y + y.y, x.z + y.z, x.w + y.w);
            x = w1[l + 192]; y = w3[l + 192]; c3 = make_float4(x.x + y.x, x.y + y.y, x.z + y.z, x.w + y.w);
        }
        float bpg = b_pgen[0];
        int row = du * 4 + w;  // [0, B*S)
        const float4* rp = (const float4*)(dec + (size_t)row * D);
        float acc = dot4(rp[l], c0) + dot4(rp[l + 64], c1) +
                    dot4(rp[l + 128], c2) + dot4(rp[l + 192], c3);
        acc = wave_sum(acc);
        if (l == 0) out1[row] = 1.0f / (1.0f + expf(-((acc + bpg) + cw)));
    } else if (r < 12) {
        // ---- A-unit: out0 pw rows (b, a of 8 s-rows) ----
        int au = g * 4 + (r - 8);  // [0,1024)
        int b = au >> 7;
        int a = au & 127;
        float inv = 1.0f / wave_sum(cs[b * 64 + l]);
        float4 v1 = e4[b * 512 + t], v2 = e4[b * 512 + 256 + t];
        float4 p1, p2;
        p1.x = v1.x * inv; p1.y = v1.y * inv; p1.z = v1.z * inv; p1.w = v1.w * inv;
        p2.x = v2.x * inv; p2.y = v2.y * inv; p2.z = v2.z * inv; p2.w = v2.w * inv;
        lds4[t] = p1;
        lds4[256 + t] = p2;
        __syncthreads();
#pragma unroll 8
        for (int it = 0; it < 16; ++it) {
            int flat = it * 256 + t;
            int s_loc = flat >> 9;
            int l4 = flat & 511;
            nt_store4(&out0[((size_t)(b * S + a * 8 + s_loc)) * 512 + l4],
                      lds4[l4]);
        }
    } else {
        // ---- B-unit: out2 quarter (b, ds) for 128 s-rows (ss) ----
        int bu = g;  // [0,256)
        int b = bu >> 5;
        int q = bu & 31;
        int ds = q & 3;
        int ss = q >> 2;
        float inv = 1.0f / wave_sum(cs[b * 64 + l]);
        int d4 = t & 63;
        int chg = t >> 6;
        float4 c = make_float4(0, 0, 0, 0);
#pragma unroll
        for (int kk = 0; kk < 16; ++kk) {
            int ch = chg + kk * 4;
            float4 p = part4[(b * 64 + ch) * 256 + ds * 64 + d4];
            c.x += p.x; c.y += p.y; c.z += p.z; c.w += p.w;
        }
        lds4[chg * 64 + d4] = c;
        __syncthreads();
        if (t < 64) {
            float4 a0 = lds4[t], a1 = lds4[64 + t], a2 = lds4[128 + t],
                   a3 = lds4[192 + t];
            float4 cx;
            cx.x = ((a0.x + a1.x) + (a2.x + a3.x)) * inv;
            cx.y = ((a0.y + a1.y) + (a2.y + a3.y)) * inv;
            cx.z = ((a0.z + a1.z) + (a2.z + a3.z)) * inv;
            cx.w = ((a0.w + a1.w) + (a2.w + a3.w)) * inv;
            lds4[256 + t] = cx;
        }
        __syncthreads();
#pragma unroll 8
        for (int it = 0; it < 32; ++it) {
            int flat = it * 256 + t;
            int s_loc = flat >> 6;
            int dloc = flat & 63;
            nt_store4(&out2[((size_t)(b * S + ss * 128 + s_loc)) * 256 +
                            ds * 64 + dloc],
                      lds4[256 + dloc]);
        }
    }
}

extern "C" void kernel_launch(void* const* d_in, const int* in_sizes, int n_in,
                              void* d_out, int out_size, void* d_ws, size_t ws_size,
                              hipStream_t stream) {
    (void)in_sizes; (void)n_in; (void)out_size; (void)ws_size;
    const float* dec = (const float*)d_in[0];
    const float* enc = (const float*)d_in[1];
    const int* mask = (const int*)d_in[2];
    const float* w_ptr = (const float*)d_in[4];
    const float* b_ptr = (const float*)d_in[5];
    const float* w_pgen = (const float*)d_in[6];
    const float* b_pgen = (const float*)d_in[7];
    float* out = (float*)d_out;
    float* ws = (float*)d_ws;

    k_enc<<<512, 256, 0, stream>>>(enc, mask, w_ptr, b_ptr, w_pgen, ws);
    k_out<<<3328, 256, 0, stream>>>(ws, dec, w_pgen, b_pgen, out);
}

// Round 10
// 36.455 us; speedup vs baseline: 4.1346x; 1.0143x over previous
//
#include <hip/hip_runtime.h>
#include <math.h>

#define B 8
#define S 1024
#define L 2048
#define D 1024

// ---- workspace layout (floats) ----
#define WS_E 0        // [B*L]    unnormalized exp scores (0 if masked)
#define WS_CS 16384   // [B*64]   per-chunk e-sums (fixed-order partials)
#define WS_PCW 16896  // [B*64]   per-chunk part·w2 dots
#define WS_PART 17408 // [B*64*D] partial unnormalized ctx

typedef float f4v __attribute__((ext_vector_type(4)));
__device__ __forceinline__ void nt_store4(float4* p, float4 v) {
    __builtin_nontemporal_store(*(f4v*)&v, (f4v*)p);
}

__device__ __forceinline__ float dot4(float4 a, float4 b) {
    return a.x * b.x + a.y * b.y + a.z * b.z + a.w * b.w;
}

__device__ __forceinline__ float wave_sum(float v) {
#pragma unroll
    for (int off = 32; off > 0; off >>= 1) v += __shfl_xor(v, off, 64);
    return v;
}

// K1: enc-only, software-pipelined. One (b,ch) chunk of 32 rows per block;
// each wave: 8 rows, 2-deep pipeline (row jj+1 loads issued before row jj math).
__global__ __launch_bounds__(256) void k_enc(const float* __restrict__ enc,
                                             const int* __restrict__ mask,
                                             const float* __restrict__ w_ptr,
                                             const float* __restrict__ b_ptr,
                                             const float* __restrict__ w_pgen,
                                             float* __restrict__ ws) {
    __shared__ float lds[4 * D];
    __shared__ float redc[4], redp[4];
    float4* lds4 = (float4*)lds;
    const int t = threadIdx.x;
    const int w = t >> 6, l = t & 63;
    const int b = blockIdx.x >> 6;
    const int ch = blockIdx.x & 63;
    const int rowbase = b * L + ch * 32 + w * 8;
    // all 8 row-masks for this wave, broadcast from lanes 0..7
    const int mymask = mask[rowbase + (l & 7)];
    const float4* wp = (const float4*)(w_ptr + D);
    float4 u0 = wp[l], u1 = wp[l + 64], u2 = wp[l + 128], u3 = wp[l + 192];
    float bp = b_ptr[0];
    float4 a0 = make_float4(0, 0, 0, 0), a1 = a0, a2 = a0, a3 = a0;
    float esum_w = 0.f;
    float4 c0, c1, c2, c3;
    int mc = __shfl(mymask, 0, 64);
    {
        const float4* rp = (const float4*)(enc + (size_t)rowbase * D);
        if (mc) { c0 = rp[l]; c1 = rp[l + 64]; c2 = rp[l + 128]; c3 = rp[l + 192]; }
    }
#pragma unroll
    for (int jj = 0; jj < 8; ++jj) {
        int mn = 0;
        float4 n0, n1, n2, n3;
        if (jj < 7) {
            mn = __shfl(mymask, jj + 1, 64);
            if (mn) {
                const float4* rp =
                    (const float4*)(enc + (size_t)(rowbase + jj + 1) * D);
                n0 = rp[l]; n1 = rp[l + 64]; n2 = rp[l + 128]; n3 = rp[l + 192];
            }
        }
        float e = 0.f;
        if (mc) {
            float pd = dot4(c0, u0) + dot4(c1, u1) + dot4(c2, u2) + dot4(c3, u3);
#pragma unroll
            for (int off = 32; off > 0; off >>= 1) pd += __shfl_xor(pd, off, 64);
            e = expf(pd + bp);
            a0.x += e * c0.x; a0.y += e * c0.y; a0.z += e * c0.z; a0.w += e * c0.w;
            a1.x += e * c1.x; a1.y += e * c1.y; a1.z += e * c1.z; a1.w += e * c1.w;
            a2.x += e * c2.x; a2.y += e * c2.y; a2.z += e * c2.z; a2.w += e * c2.w;
            a3.x += e * c3.x; a3.y += e * c3.y; a3.z += e * c3.z; a3.w += e * c3.w;
        }
        esum_w += e;
        if (l == 0) ws[WS_E + rowbase + jj] = e;
        mc = mn; c0 = n0; c1 = n1; c2 = n2; c3 = n3;
    }
    float4* lp = lds4 + w * 256;
    lp[l] = a0; lp[l + 64] = a1; lp[l + 128] = a2; lp[l + 192] = a3;
    if (l == 0) redc[w] = esum_w;
    __syncthreads();
    float4 s0 = lds4[t], s1 = lds4[256 + t], s2 = lds4[512 + t], s3 = lds4[768 + t];
    float4 r;
    r.x = (s0.x + s1.x) + (s2.x + s3.x);
    r.y = (s0.y + s1.y) + (s2.y + s3.y);
    r.z = (s0.z + s1.z) + (s2.z + s3.z);
    r.w = (s0.w + s1.w) + (s2.w + s3.w);
    ((float4*)(ws + WS_PART))[(b * 64 + ch) * 256 + t] = r;
    // pcw: this chunk's contribution to ctx·w2 (fixed-order)
    float4 w2v = ((const float4*)(w_pgen + D))[t];
    float pc = wave_sum(dot4(r, w2v));
    if (l == 0) redp[w] = pc;
    __syncthreads();
    if (t == 0) {
        ws[WS_CS + b * 64 + ch] = (redc[0] + redc[1]) + (redc[2] + redc[3]);
        ws[WS_PCW + b * 64 + ch] = (redp[0] + redp[1]) + (redp[2] + redp[3]);
    }
}

// K2: 3328 blocks, roles interleaved by bid%13 so dec reads co-flow with writes:
//   r in [0,8):  D — 4 dec rows -> out1 (cw recomputed from cs/pcw scalars)
//   r in [8,12): A — out0: 8 pw rows (64 KB nt-stores)
//   r == 12:     B — out2: quarter-tile, 128 s-rows (128 KB nt-stores)
__global__ __launch_bounds__(256) void k_out(const float* __restrict__ ws,
                                             const float* __restrict__ dec,
                                             const float* __restrict__ w_pgen,
                                             const float* __restrict__ b_pgen,
                                             float* __restrict__ out) {
    __shared__ float4 lds4[512];
    const int t = threadIdx.x;
    const int w = t >> 6, l = t & 63;
    const int g = blockIdx.x / 13;
    const int r = blockIdx.x % 13;
    const float4* e4 = (const float4*)(ws + WS_E);
    const float4* part4 = (const float4*)(ws + WS_PART);
    const float* cs = ws + WS_CS;
    const float* pcw = ws + WS_PCW;
    float4* out0 = (float4*)out;
    float* out1 = out + (size_t)B * S * L;
    float4* out2 = (float4*)(out + (size_t)B * S * L + B * S);

    if (r < 8) {
        // ---- D-unit: 4 dec rows -> out1 ----
        int du = g * 8 + r;  // [0,2048)
        int b = du >> 8;
        float inv = 1.0f / wave_sum(cs[b * 64 + l]);
        float cw = inv * wave_sum(pcw[b * 64 + l]);
        const float4* w1 = (const float4*)(w_pgen);
        const float4* w3 = (const float4*)(w_pgen + 2 * D);
        float4 c0, c1, c2, c3;
        {
            float4 x, y;
            x = w1[l];       y = w3[l];       c0 = make_float4(x.x + y.x, x.y + y.y, x.z + y.z, x.w + y.w);
            x = w1[l + 64];  y = w3[l + 64];  c1 = make_float4(x.x + y.x, x.y + y.y, x.z + y.z, x.w + y.w);
            x = w1[l + 128]; y = w3[l + 128]; c2 = make_float4(x.x + y.x, x.y + y.y, x.z + y.z, x.w + y.w);
            x = w1[l + 192]; y = w3[l + 192]; c3 = make_float4(x.x + y.x, x.y + y.y, x.z + y.z, x.w + y.w);
        }
        float bpg = b_pgen[0];
        int row = du * 4 + w;  // [0, B*S)
        const float4* rp = (const float4*)(dec + (size_t)row * D);
        float acc = dot4(rp[l], c0) + dot4(rp[l + 64], c1) +
                    dot4(rp[l + 128], c2) + dot4(rp[l + 192], c3);
        acc = wave_sum(acc);
        if (l == 0) out1[row] = 1.0f / (1.0f + expf(-((acc + bpg) + cw)));
    } else if (r < 12) {
        // ---- A-unit: out0 pw rows (b, a of 8 s-rows) ----
        int au = g * 4 + (r - 8);  // [0,1024)
        int b = au >> 7;
        int a = au & 127;
        float inv = 1.0f / wave_sum(cs[b * 64 + l]);
        float4 v1 = e4[b * 512 + t], v2 = e4[b * 512 + 256 + t];
        float4 p1, p2;
        p1.x = v1.x * inv; p1.y = v1.y * inv; p1.z = v1.z * inv; p1.w = v1.w * inv;
        p2.x = v2.x * inv; p2.y = v2.y * inv; p2.z = v2.z * inv; p2.w = v2.w * inv;
        lds4[t] = p1;
        lds4[256 + t] = p2;
        __syncthreads();
#pragma unroll 8
        for (int it = 0; it < 16; ++it) {
            int flat = it * 256 + t;
            int s_loc = flat >> 9;
            int l4 = flat & 511;
            nt_store4(&out0[((size_t)(b * S + a * 8 + s_loc)) * 512 + l4],
                      lds4[l4]);
        }
    } else {
        // ---- B-unit: out2 quarter (b, ds) for 128 s-rows (ss) ----
        int bu = g;  // [0,256)
        int b = bu >> 5;
        int q = bu & 31;
        int ds = q & 3;
        int ss = q >> 2;
        float inv = 1.0f / wave_sum(cs[b * 64 + l]);
        int d4 = t & 63;
        int chg = t >> 6;
        float4 c = make_float4(0, 0, 0, 0);
#pragma unroll
        for (int kk = 0; kk < 16; ++kk) {
            int ch = chg + kk * 4;
            float4 p = part4[(b * 64 + ch) * 256 + ds * 64 + d4];
            c.x += p.x; c.y += p.y; c.z += p.z; c.w += p.w;
        }
        lds4[chg * 64 + d4] = c;
        __syncthreads();
        if (t < 64) {
            float4 a0 = lds4[t], a1 = lds4[64 + t], a2 = lds4[128 + t],
                   a3 = lds4[192 + t];
            float4 cx;
            cx.x = ((a0.x + a1.x) + (a2.x + a3.x)) * inv;
            cx.y = ((a0.y + a1.y) + (a2.y + a3.y)) * inv;
            cx.z = ((a0.z + a1.z) + (a2.z + a3.z)) * inv;
            cx.w = ((a0.w + a1.w) + (a2.w + a3.w)) * inv;
            lds4[256 + t] = cx;
        }
        __syncthreads();
#pragma unroll 8
        for (int it = 0; it < 32; ++it) {
            int flat = it * 256 + t;
            int s_loc = flat >> 6;
            int dloc = flat & 63;
            nt_store4(&out2[((size_t)(b * S + ss * 128 + s_loc)) * 256 +
                            ds * 64 + dloc],
                      lds4[256 + dloc]);
        }
    }
}

extern "C" void kernel_launch(void* const* d_in, const int* in_sizes, int n_in,
                              void* d_out, int out_size, void* d_ws, size_t ws_size,
                              hipStream_t stream) {
    (void)in_sizes; (void)n_in; (void)out_size; (void)ws_size;
    const float* dec = (const float*)d_in[0];
    const float* enc = (const float*)d_in[1];
    const int* mask = (const int*)d_in[2];
    const float* w_ptr = (const float*)d_in[4];
    const float* b_ptr = (const float*)d_in[5];
    const float* w_pgen = (const float*)d_in[6];
    const float* b_pgen = (const float*)d_in[7];
    float* out = (float*)d_out;
    float* ws = (float*)d_ws;

    k_enc<<<512, 256, 0, stream>>>(enc, mask, w_ptr, b_ptr, w_pgen, ws);
    k_out<<<3328, 256, 0, stream>>>(ws, dec, w_pgen, b_pgen, out);
}